// Round 12
// baseline (141.412 us; speedup 1.0000x reference)
//
#include <hip/hip_runtime.h>
#include <hip/hip_bf16.h>

// SConv: x(8,64,128,128) f32, Coefficient(9,9), W(128,64,3,3), b(128)
// out[b,co,h,w] = sum_{c,t} z[b,c,h,w][t] * W[co,c,t] + b[co]
// z = [sorted8(y[noncenter])[0:4], center, sorted8[4:8]],
// y_i = sum_j Coefficient[i,j] * patch_j (3x3 neighborhood, zero pad 1).
//
// Round 19 = REVERT to R11 (best measured: 61.4 us kernel; every structural
// variant since landed 61-68 normalized or worse) + ONE untested ILP fix:
//  - Phase B accumulator SPLIT: R11 ran a single 36-deep dependent MFMA
//    chain (acc = mfma(a,b,acc)). If 32x32x16 dependent latency > ~8cy
//    issue, that chain exposes matrix-pipe bubbles (MfmaUtil was only 12%).
//    Now acc_e (even ks) and acc_o (odd ks), merged with 16 v_add at the
//    epilogue: dep spacing 2, +32 VGPR (52 -> ~84, under the 128 cap).
// Everything else is R11 verbatim: MT=64 (4h x 16w), 8 waves = 2m x 4n,
// MFMA 32x32x16, A 4-deep ds-queue + B 8-deep global-queue issued before
// the barrier, XOR-swizzled Z stores (sw=pw<<4), SROW 600, LDS 76.8 KB.
// Layouts: A row=lane&31, k=(lane>>5)*8+e; C/D col=lane&31=co,
// row=(reg&3)+8*(reg>>2)+4*(lane>>5) (m74/m101).

#define B_   8
#define C_   64
#define H_   128
#define W_   128
#define CO_  128
#define K_   576    // C_*9 = 36*16
#define MT   64     // sites per block (4h x 16w)
#define SROW 600    // LDS row stride in elements (1200 B)

typedef __attribute__((ext_vector_type(8)))  short  short8;
typedef __attribute__((ext_vector_type(8)))  __bf16 bf16x8;
typedef __attribute__((ext_vector_type(16))) float  f32x16;
typedef __attribute__((ext_vector_type(2)))  float  f32x2;

__device__ __forceinline__ void cswap2(f32x2 &a, f32x2 &b) {
    f32x2 lo = __builtin_elementwise_min(a, b);
    f32x2 hi = __builtin_elementwise_max(a, b);
    a = lo; b = hi;
}

__device__ __forceinline__ ushort f2bf(float f) {
    union { float f; unsigned u; } v; v.f = f;
    unsigned r = v.u + 0x7fffu + ((v.u >> 16) & 1u);  // RNE
    return (ushort)(r >> 16);
}

__device__ __forceinline__ unsigned pack2bf(float lo, float hi) {
    union { __hip_bfloat162 h; unsigned u; } cv;
    cv.h = __float22bfloat162_rn(make_float2(lo, hi));  // x->low word
    return cv.u;
}

// Repack W[co][k] f32 -> Wb[((nt*36+ks)*64+lane)*8+e] bf16 where
// co = nt*32+(lane&31), k = ks*16+(lane>>5)*8+e. One contiguous 1 KB line
// per (nt,ks) = exactly one wave-fragment.
__global__ __launch_bounds__(256) void conv_W_bf16(const float* __restrict__ Wg,
                                                   ushort* __restrict__ Wb) {
    int i = blockIdx.x * 256 + threadIdx.x;
    if (i >= CO_ * K_) return;
    const int e    = i & 7;
    const int lane = (i >> 3) & 63;
    const int t    = i >> 9;            // nt*36 + ks
    const int nt   = t / 36;
    const int ks   = t - nt * 36;
    const int co   = nt * 32 + (lane & 31);
    const int k    = ks * 16 + (lane >> 5) * 8 + e;
    Wb[i] = f2bf(Wg[co * K_ + k]);
}

__global__ __launch_bounds__(512, 4) void sconv_mfma(
    const float* __restrict__ x,
    const float* __restrict__ Coef,
    const ushort* __restrict__ Wb,     // bf16 bits, repacked (see above)
    const float* __restrict__ bias,
    float* __restrict__ out)
{
    __shared__ __align__(16) ushort Zl[MT * SROW];   // 76800 B -> 2 blocks/CU

    const int tid = threadIdx.x;
    const int bx  = blockIdx.x;
    const int wq  = bx & 7;            // 16-wide w slice
    const int hq  = (bx >> 3) & 31;    // h quad index
    const int b   = bx >> 8;
    const int w0  = wq * 16;
    const int h0  = hq * 4;

    // Phase-B addressing hoisted: B prefetch is issued BEFORE the barrier.
    const int wave = tid >> 6;
    const int lane = tid & 63;
    const int mt   = wave >> 2;        // m-tile: Z rows mt*32..+31
    const int nt   = wave & 3;         // n-tile: co nt*32..+31
    const int r31  = lane & 31;
    const int u    = lane >> 5;
    const ushort* bptr = Wb + ((size_t)(nt * 36) * 64 + lane) * 8;

    // ---- Phase A: z for 64 c x (4h x 16w); 2w x 4h sites per thread ----
    {
        // c = wave + 8*j: all c in a wave share parity(9c) -> uniform branch
        const int j  = (tid >> 3) & 7;
        const int c  = wave + 8 * j;
        const int pw = tid & 7;                // 8 w-pairs
        const int w  = w0 + pw * 2;
        const float* xb = x + ((size_t)(b * C_ + c)) * (H_ * W_);

        // 6 rows x 4 cols of padded input (covers 2w x 4h sites' patches)
        float r[6][4];
        const bool interior = (h0 >= 4) && (h0 <= 120) && (w0 >= 16) && (w0 <= 96);
        if (interior) {                        // block-uniform: scalar branch
            const float* bp = xb + (h0 - 1) * W_ + (w - 1);
            #pragma unroll
            for (int dy = 0; dy < 6; ++dy) {
                float4 v; __builtin_memcpy(&v, bp + dy * W_, 16);  // dwordx4 @4B align
                r[dy][0] = v.x; r[dy][1] = v.y; r[dy][2] = v.z; r[dy][3] = v.w;
            }
        } else {
            // branch-free clamped loads + selects (no per-lane divergence)
            const int wm = w - 1;
            const int wc = min(max(wm, 0), W_ - 4);
            const int s  = wm - wc;            // -1 (left pad), 0, +1 (right pad)
            #pragma unroll
            for (int dy = 0; dy < 6; ++dy) {
                const int hy  = h0 + dy - 1;
                const bool hok = (unsigned)hy < (unsigned)H_;
                const int hc  = min(max(hy, 0), H_ - 1);
                float4 v; __builtin_memcpy(&v, xb + hc * W_ + wc, 16);
                const float rr0 = (s < 0) ? 0.f : ((s > 0) ? v.y : v.x);
                const float rr1 = (s < 0) ? v.x : ((s > 0) ? v.z : v.y);
                const float rr2 = (s < 0) ? v.y : ((s > 0) ? v.w : v.z);
                const float rr3 = (s < 0) ? v.z : ((s > 0) ? 0.f : v.w);
                r[dy][0] = hok ? rr0 : 0.f;
                r[dy][1] = hok ? rr1 : 0.f;
                r[dy][2] = hok ? rr2 : 0.f;
                r[dy][3] = hok ? rr3 : 0.f;
            }
        }

        const int k0 = c * 9;
        const int sw = pw << 4;                // store swizzle
        #pragma unroll
        for (int hl = 0; hl < 4; ++hl) {       // adjacent h-sites share rows
            f32x2 p2[9];
            #pragma unroll
            for (int dy = 0; dy < 3; ++dy)
                #pragma unroll
                for (int dx = 0; dx < 3; ++dx)
                    p2[dy * 3 + dx] = (f32x2){ r[hl + dy][dx], r[hl + dy][dx + 1] };

            // y_i for i in {0,1,2,3,5,6,7,8}; Coef via uniform (scalar) loads
            f32x2 v2[8];
            #pragma unroll
            for (int ii = 0; ii < 8; ++ii) {
                const int i = ii + (ii >> 2);
                f32x2 acc = p2[0] * Coef[i * 9];
                #pragma unroll
                for (int jj = 1; jj < 9; ++jj) acc += p2[jj] * Coef[i * 9 + jj];
                v2[ii] = acc;
            }

            // Batcher odd-even mergesort, 8 elems, ascending (19 comparators)
            cswap2(v2[0],v2[1]); cswap2(v2[2],v2[3]); cswap2(v2[4],v2[5]); cswap2(v2[6],v2[7]);
            cswap2(v2[0],v2[2]); cswap2(v2[1],v2[3]); cswap2(v2[4],v2[6]); cswap2(v2[5],v2[7]);
            cswap2(v2[1],v2[2]); cswap2(v2[5],v2[6]);
            cswap2(v2[0],v2[4]); cswap2(v2[1],v2[5]); cswap2(v2[2],v2[6]); cswap2(v2[3],v2[7]);
            cswap2(v2[2],v2[4]); cswap2(v2[3],v2[5]);
            cswap2(v2[1],v2[2]); cswap2(v2[3],v2[4]); cswap2(v2[5],v2[6]);

            f32x2 z2[9] = { v2[0], v2[1], v2[2], v2[3], p2[4],
                            v2[4], v2[5], v2[6], v2[7] };

            // Z rows m = hl*16 + (pw*2, pw*2+1); byte offsets XOR sw
            char* zb0 = (char*)Zl + (size_t)(hl * 16 + pw * 2) * (SROW * 2);
            char* zb1 = zb0 + SROW * 2;
            if ((k0 & 1) == 0) {                    // wave-uniform branch
                #pragma unroll
                for (int q = 0; q < 4; ++q) {
                    *(unsigned*)(zb0 + (((k0 + 2*q) * 2) ^ sw)) = pack2bf(z2[2*q][0], z2[2*q+1][0]);
                    *(unsigned*)(zb1 + (((k0 + 2*q) * 2) ^ sw)) = pack2bf(z2[2*q][1], z2[2*q+1][1]);
                }
                *(ushort*)(zb0 + (((k0 + 8) * 2) ^ sw)) = f2bf(z2[8][0]);
                *(ushort*)(zb1 + (((k0 + 8) * 2) ^ sw)) = f2bf(z2[8][1]);
            } else {                                // single at k0, pairs k0+1..
                *(ushort*)(zb0 + ((k0 * 2) ^ sw)) = f2bf(z2[0][0]);
                *(ushort*)(zb1 + ((k0 * 2) ^ sw)) = f2bf(z2[0][1]);
                #pragma unroll
                for (int q = 0; q < 4; ++q) {
                    *(unsigned*)(zb0 + (((k0 + 1 + 2*q) * 2) ^ sw)) = pack2bf(z2[1+2*q][0], z2[2+2*q][0]);
                    *(unsigned*)(zb1 + (((k0 + 1 + 2*q) * 2) ^ sw)) = pack2bf(z2[1+2*q][1], z2[2+2*q][1]);
                }
            }
        }
    }

    // ---- B prefetch (independent of Phase A): hide L2 latency under barrier
    short8 bq[8];
    #pragma unroll
    for (int i = 0; i < 8; ++i) bq[i] = *(const short8*)(bptr + i * 512);

    __syncthreads();

    // ---- Phase B: 32x32x16 MFMA GEMM  out[m, n=co] = sum_k Z[m,k]W^T[n,k]
    const int arow = mt * 32 + r31;
    const char* abase = (const char*)Zl + (size_t)arow * (SROW * 2);
    const int aswz = ((arow >> 1) & 7) << 4;
    // 4 swizzled base pointers; all 36 ds_reads use immediate offsets.
    const char* pj[4];
    #pragma unroll
    for (int j = 0; j < 4; ++j)
        pj[j] = abase + (((j * 32) | (u * 16)) ^ aswz);

    bf16x8 aq[4];
    #pragma unroll
    for (int i = 0; i < 4; ++i)
        aq[i] = *(const bf16x8*)(pj[i & 3] + (i >> 2) * 128);

    // Dual accumulators: even/odd ks -> dependent-MFMA spacing 2
    f32x16 acc_e = {}, acc_o = {};

    #pragma unroll
    for (int ks = 0; ks < 36; ++ks) {
        bf16x8 a  = aq[ks & 3];
        short8 bb = bq[ks & 7];
        if (ks + 4 < 36)
            aq[ks & 3] = *(const bf16x8*)(pj[(ks + 4) & 3] + ((ks + 4) >> 2) * 128);
        if (ks + 8 < 36)
            bq[ks & 7] = *(const short8*)(bptr + (ks + 8) * 512);
        if ((ks & 1) == 0)
            acc_e = __builtin_amdgcn_mfma_f32_32x32x16_bf16(a, __builtin_bit_cast(bf16x8, bb), acc_e, 0, 0, 0);
        else
            acc_o = __builtin_amdgcn_mfma_f32_32x32x16_bf16(a, __builtin_bit_cast(bf16x8, bb), acc_o, 0, 0, 0);
    }
    f32x16 acc = acc_e + acc_o;

    // ---- Epilogue: D col=lane&31 -> co-local; row=(reg&3)+8*(reg>>2)+4*u
    const int co = nt * 32 + r31;
    const float bv = bias[co];
    float* obase = out + (((size_t)(b * CO_ + co)) * H_ + h0 + mt * 2) * W_ + w0;
    #pragma unroll
    for (int qq = 0; qq < 4; ++qq) {
        const int roff = qq * 8 + u * 4;       // m-local base, multiple of 4
        const int hl   = roff >> 4;            // 0 or 1 within this m-tile
        const int wl   = roff & 15;            // 0,4,8,12
        float4 vv = make_float4(acc[qq*4+0] + bv, acc[qq*4+1] + bv,
                                acc[qq*4+2] + bv, acc[qq*4+3] + bv);
        *(float4*)(obase + hl * W_ + wl) = vv;
    }
}

// ---- fp32 fallback (round-1 kernel, direct W layout) if ws is too small ----
#define WT 16
__device__ __forceinline__ void cswap(float &a, float &b) {
    float lo = fminf(a, b);
    float hi = fmaxf(a, b);
    a = lo; b = hi;
}
__global__ __launch_bounds__(256) void sconv_fp32(
    const float* __restrict__ x, const float* __restrict__ Coef,
    const float* __restrict__ Wg, const float* __restrict__ bias,
    float* __restrict__ out)
{
    __shared__ float Cf[81];
    __shared__ float Zl[C_ * 9 * WT];
    const int tid = threadIdx.x;
    const int bx  = blockIdx.x;
    const int wt  = bx & 7;
    const int h   = (bx >> 3) & 127;
    const int b   = bx >> 10;
    const int w0  = wt * WT;
    if (tid < 81) Cf[tid] = Coef[tid];
    __syncthreads();
    for (int task = tid; task < C_ * WT; task += 256) {
        const int c = task >> 4, wl = task & 15, w = w0 + wl;
        const float* xb = x + (b * C_ + c) * H_ * W_;
        float p[9];
        #pragma unroll
        for (int dy = 0; dy < 3; ++dy) {
            const int hy = h + dy - 1; const bool hin = (unsigned)hy < (unsigned)H_;
            #pragma unroll
            for (int dx = 0; dx < 3; ++dx) {
                const int wx = w + dx - 1; const bool win = (unsigned)wx < (unsigned)W_;
                p[dy * 3 + dx] = (hin && win) ? xb[hy * W_ + wx] : 0.0f;
            }
        }
        float v[8];
        #pragma unroll
        for (int ii = 0; ii < 8; ++ii) {
            const int i = ii + (ii >> 2);
            float acc = 0.0f;
            #pragma unroll
            for (int jj = 0; jj < 9; ++jj) acc = fmaf(Cf[i * 9 + jj], p[jj], acc);
            v[ii] = acc;
        }
        cswap(v[0], v[1]); cswap(v[2], v[3]); cswap(v[4], v[5]); cswap(v[6], v[7]);
        cswap(v[0], v[2]); cswap(v[1], v[3]); cswap(v[4], v[6]); cswap(v[5], v[7]);
        cswap(v[1], v[2]); cswap(v[5], v[6]);
        cswap(v[0], v[4]); cswap(v[1], v[5]); cswap(v[2], v[6]); cswap(v[3], v[7]);
        cswap(v[2], v[4]); cswap(v[3], v[5]);
        cswap(v[1], v[2]); cswap(v[3], v[4]); cswap(v[5], v[6]);
        const int base = c * 9 * WT + wl;
        Zl[base + 0*WT]=v[0]; Zl[base + 1*WT]=v[1]; Zl[base + 2*WT]=v[2]; Zl[base + 3*WT]=v[3];
        Zl[base + 4*WT]=p[4];
        Zl[base + 5*WT]=v[4]; Zl[base + 6*WT]=v[5]; Zl[base + 7*WT]=v[6]; Zl[base + 8*WT]=v[7];
    }
    __syncthreads();
    const int co = tid >> 1, w0l = (tid & 1) * 8;
    float acc[8];
    #pragma unroll
    for (int i = 0; i < 8; ++i) acc[i] = 0.0f;
    for (int c = 0; c < C_; ++c) {
        #pragma unroll
        for (int t = 0; t < 9; ++t) {
            const float wv = Wg[(co * C_ + c) * 9 + t];
            const float* zp = &Zl[(c * 9 + t) * WT + w0l];
            const float4 za = *(const float4*)zp;
            const float4 zb = *(const float4*)(zp + 4);
            acc[0]=fmaf(za.x,wv,acc[0]); acc[1]=fmaf(za.y,wv,acc[1]);
            acc[2]=fmaf(za.z,wv,acc[2]); acc[3]=fmaf(za.w,wv,acc[3]);
            acc[4]=fmaf(zb.x,wv,acc[4]); acc[5]=fmaf(zb.y,wv,acc[5]);
            acc[6]=fmaf(zb.z,wv,acc[6]); acc[7]=fmaf(zb.w,wv,acc[7]);
        }
    }
    const float bv = bias[co];
    float* op = out + ((b * CO_ + co) * H_ + h) * W_ + w0 + w0l;
    *(float4*)(op)     = make_float4(acc[0]+bv, acc[1]+bv, acc[2]+bv, acc[3]+bv);
    *(float4*)(op + 4) = make_float4(acc[4]+bv, acc[5]+bv, acc[6]+bv, acc[7]+bv);
}

extern "C" void kernel_launch(void* const* d_in, const int* in_sizes, int n_in,
                              void* d_out, int out_size, void* d_ws, size_t ws_size,
                              hipStream_t stream) {
    const float* x    = (const float*)d_in[0];
    const float* Coef = (const float*)d_in[1];
    const float* Wg   = (const float*)d_in[2];
    const float* bias = (const float*)d_in[3];
    float* out = (float*)d_out;

    const size_t need = (size_t)CO_ * K_ * sizeof(ushort);   // 147456 B
    if (ws_size >= need) {
        ushort* Wb = (ushort*)d_ws;
        conv_W_bf16<<<(CO_ * K_ + 255) / 256, 256, 0, stream>>>(Wg, Wb);
        sconv_mfma<<<B_ * (H_ / 4) * (W_ / 16), 512, 0, stream>>>(x, Coef, Wb, bias, out);
    } else {
        sconv_fp32<<<B_ * H_ * 8, 256, 0, stream>>>(x, Coef, Wg, bias, out);
    }
}

// Round 13
// 136.777 us; speedup vs baseline: 1.0339x; 1.0339x over previous
//
#include <hip/hip_runtime.h>
#include <hip/hip_bf16.h>

// SConv: x(8,64,128,128) f32, Coefficient(9,9), W(128,64,3,3), b(128)
// out[b,co,h,w] = sum_{c,t} z[b,c,h,w][t] * W[co,c,t] + b[co]
// z = [sorted8(y[noncenter])[0:4], center, sorted8[4:8]],
// y_i = sum_j Coefficient[i,j] * patch_j (3x3 neighborhood, zero pad 1).
//
// FINAL (Round 20) = exact restore of the session's best verified kernel
// (R11 source: 61.4 us kernel, 137.7 us harness). Session findings:
//  - Latency plateau ~62-68 us: NOT a pipe roofline (VALU ~32%, MFMA ~10%,
//    HBM ~21%). Isolated-and-null: bank conflicts (6.3M->1.8M, no change),
//    occupancy (37->54%, no change), tile software-pipelining, producer/
//    consumer wave specialization. Regressions: raw s_barrier+"memory"
//    (spills: FETCH 64->212MB), depth-2 row prefetch (+state, +20us),
//    dual accumulators (queue squeeze at fixed VGPR budget).
//  - Structure: MT=64 sites (4h x 16w), 8 waves = 2 m-tiles x 4 n-tiles,
//    MFMA 32x32x16, W repacked so each wave-fragment is one contiguous
//    1 KB line; A 4-deep ds-queue + B 8-deep global-queue issued BEFORE
//    the barrier; XOR-swizzled Z stores; SROW 600; LDS 76.8 KB.
// Layouts: A row=lane&31, k=(lane>>5)*8+e; C/D col=lane&31=co,
// row=(reg&3)+8*(reg>>2)+4*(lane>>5) (m74/m101).

#define B_   8
#define C_   64
#define H_   128
#define W_   128
#define CO_  128
#define K_   576    // C_*9 = 36*16
#define MT   64     // sites per block (4h x 16w)
#define SROW 600    // LDS row stride in elements (1200 B)

typedef __attribute__((ext_vector_type(8)))  short  short8;
typedef __attribute__((ext_vector_type(8)))  __bf16 bf16x8;
typedef __attribute__((ext_vector_type(16))) float  f32x16;
typedef __attribute__((ext_vector_type(2)))  float  f32x2;

__device__ __forceinline__ void cswap2(f32x2 &a, f32x2 &b) {
    f32x2 lo = __builtin_elementwise_min(a, b);
    f32x2 hi = __builtin_elementwise_max(a, b);
    a = lo; b = hi;
}

__device__ __forceinline__ ushort f2bf(float f) {
    union { float f; unsigned u; } v; v.f = f;
    unsigned r = v.u + 0x7fffu + ((v.u >> 16) & 1u);  // RNE
    return (ushort)(r >> 16);
}

__device__ __forceinline__ unsigned pack2bf(float lo, float hi) {
    union { __hip_bfloat162 h; unsigned u; } cv;
    cv.h = __float22bfloat162_rn(make_float2(lo, hi));  // x->low word
    return cv.u;
}

// Repack W[co][k] f32 -> Wb[((nt*36+ks)*64+lane)*8+e] bf16 where
// co = nt*32+(lane&31), k = ks*16+(lane>>5)*8+e. One contiguous 1 KB line
// per (nt,ks) = exactly one wave-fragment.
__global__ __launch_bounds__(256) void conv_W_bf16(const float* __restrict__ Wg,
                                                   ushort* __restrict__ Wb) {
    int i = blockIdx.x * 256 + threadIdx.x;
    if (i >= CO_ * K_) return;
    const int e    = i & 7;
    const int lane = (i >> 3) & 63;
    const int t    = i >> 9;            // nt*36 + ks
    const int nt   = t / 36;
    const int ks   = t - nt * 36;
    const int co   = nt * 32 + (lane & 31);
    const int k    = ks * 16 + (lane >> 5) * 8 + e;
    Wb[i] = f2bf(Wg[co * K_ + k]);
}

__global__ __launch_bounds__(512, 4) void sconv_mfma(
    const float* __restrict__ x,
    const float* __restrict__ Coef,
    const ushort* __restrict__ Wb,     // bf16 bits, repacked (see above)
    const float* __restrict__ bias,
    float* __restrict__ out)
{
    __shared__ __align__(16) ushort Zl[MT * SROW];   // 76800 B -> 2 blocks/CU

    const int tid = threadIdx.x;
    const int bx  = blockIdx.x;
    const int wq  = bx & 7;            // 16-wide w slice
    const int hq  = (bx >> 3) & 31;    // h quad index
    const int b   = bx >> 8;
    const int w0  = wq * 16;
    const int h0  = hq * 4;

    // Phase-B addressing hoisted: B prefetch is issued BEFORE the barrier.
    const int wave = tid >> 6;
    const int lane = tid & 63;
    const int mt   = wave >> 2;        // m-tile: Z rows mt*32..+31
    const int nt   = wave & 3;         // n-tile: co nt*32..+31
    const int r31  = lane & 31;
    const int u    = lane >> 5;
    const ushort* bptr = Wb + ((size_t)(nt * 36) * 64 + lane) * 8;

    // ---- Phase A: z for 64 c x (4h x 16w); 2w x 4h sites per thread ----
    {
        // c = wave + 8*j: all c in a wave share parity(9c) -> uniform branch
        const int j  = (tid >> 3) & 7;
        const int c  = wave + 8 * j;
        const int pw = tid & 7;                // 8 w-pairs
        const int w  = w0 + pw * 2;
        const float* xb = x + ((size_t)(b * C_ + c)) * (H_ * W_);

        // 6 rows x 4 cols of padded input (covers 2w x 4h sites' patches)
        float r[6][4];
        const bool interior = (h0 >= 4) && (h0 <= 120) && (w0 >= 16) && (w0 <= 96);
        if (interior) {                        // block-uniform: scalar branch
            const float* bp = xb + (h0 - 1) * W_ + (w - 1);
            #pragma unroll
            for (int dy = 0; dy < 6; ++dy) {
                float4 v; __builtin_memcpy(&v, bp + dy * W_, 16);  // dwordx4 @4B align
                r[dy][0] = v.x; r[dy][1] = v.y; r[dy][2] = v.z; r[dy][3] = v.w;
            }
        } else {
            // branch-free clamped loads + selects (no per-lane divergence)
            const int wm = w - 1;
            const int wc = min(max(wm, 0), W_ - 4);
            const int s  = wm - wc;            // -1 (left pad), 0, +1 (right pad)
            #pragma unroll
            for (int dy = 0; dy < 6; ++dy) {
                const int hy  = h0 + dy - 1;
                const bool hok = (unsigned)hy < (unsigned)H_;
                const int hc  = min(max(hy, 0), H_ - 1);
                float4 v; __builtin_memcpy(&v, xb + hc * W_ + wc, 16);
                const float rr0 = (s < 0) ? 0.f : ((s > 0) ? v.y : v.x);
                const float rr1 = (s < 0) ? v.x : ((s > 0) ? v.z : v.y);
                const float rr2 = (s < 0) ? v.y : ((s > 0) ? v.w : v.z);
                const float rr3 = (s < 0) ? v.z : ((s > 0) ? 0.f : v.w);
                r[dy][0] = hok ? rr0 : 0.f;
                r[dy][1] = hok ? rr1 : 0.f;
                r[dy][2] = hok ? rr2 : 0.f;
                r[dy][3] = hok ? rr3 : 0.f;
            }
        }

        const int k0 = c * 9;
        const int sw = pw << 4;                // store swizzle
        #pragma unroll
        for (int hl = 0; hl < 4; ++hl) {       // adjacent h-sites share rows
            f32x2 p2[9];
            #pragma unroll
            for (int dy = 0; dy < 3; ++dy)
                #pragma unroll
                for (int dx = 0; dx < 3; ++dx)
                    p2[dy * 3 + dx] = (f32x2){ r[hl + dy][dx], r[hl + dy][dx + 1] };

            // y_i for i in {0,1,2,3,5,6,7,8}; Coef via uniform (scalar) loads
            f32x2 v2[8];
            #pragma unroll
            for (int ii = 0; ii < 8; ++ii) {
                const int i = ii + (ii >> 2);
                f32x2 acc = p2[0] * Coef[i * 9];
                #pragma unroll
                for (int jj = 1; jj < 9; ++jj) acc += p2[jj] * Coef[i * 9 + jj];
                v2[ii] = acc;
            }

            // Batcher odd-even mergesort, 8 elems, ascending (19 comparators)
            cswap2(v2[0],v2[1]); cswap2(v2[2],v2[3]); cswap2(v2[4],v2[5]); cswap2(v2[6],v2[7]);
            cswap2(v2[0],v2[2]); cswap2(v2[1],v2[3]); cswap2(v2[4],v2[6]); cswap2(v2[5],v2[7]);
            cswap2(v2[1],v2[2]); cswap2(v2[5],v2[6]);
            cswap2(v2[0],v2[4]); cswap2(v2[1],v2[5]); cswap2(v2[2],v2[6]); cswap2(v2[3],v2[7]);
            cswap2(v2[2],v2[4]); cswap2(v2[3],v2[5]);
            cswap2(v2[1],v2[2]); cswap2(v2[3],v2[4]); cswap2(v2[5],v2[6]);

            f32x2 z2[9] = { v2[0], v2[1], v2[2], v2[3], p2[4],
                            v2[4], v2[5], v2[6], v2[7] };

            // Z rows m = hl*16 + (pw*2, pw*2+1); byte offsets XOR sw
            char* zb0 = (char*)Zl + (size_t)(hl * 16 + pw * 2) * (SROW * 2);
            char* zb1 = zb0 + SROW * 2;
            if ((k0 & 1) == 0) {                    // wave-uniform branch
                #pragma unroll
                for (int q = 0; q < 4; ++q) {
                    *(unsigned*)(zb0 + (((k0 + 2*q) * 2) ^ sw)) = pack2bf(z2[2*q][0], z2[2*q+1][0]);
                    *(unsigned*)(zb1 + (((k0 + 2*q) * 2) ^ sw)) = pack2bf(z2[2*q][1], z2[2*q+1][1]);
                }
                *(ushort*)(zb0 + (((k0 + 8) * 2) ^ sw)) = f2bf(z2[8][0]);
                *(ushort*)(zb1 + (((k0 + 8) * 2) ^ sw)) = f2bf(z2[8][1]);
            } else {                                // single at k0, pairs k0+1..
                *(ushort*)(zb0 + ((k0 * 2) ^ sw)) = f2bf(z2[0][0]);
                *(ushort*)(zb1 + ((k0 * 2) ^ sw)) = f2bf(z2[0][1]);
                #pragma unroll
                for (int q = 0; q < 4; ++q) {
                    *(unsigned*)(zb0 + (((k0 + 1 + 2*q) * 2) ^ sw)) = pack2bf(z2[1+2*q][0], z2[2+2*q][0]);
                    *(unsigned*)(zb1 + (((k0 + 1 + 2*q) * 2) ^ sw)) = pack2bf(z2[1+2*q][1], z2[2+2*q][1]);
                }
            }
        }
    }

    // ---- B prefetch (independent of Phase A): hide L2 latency under barrier
    short8 bq[8];
    #pragma unroll
    for (int i = 0; i < 8; ++i) bq[i] = *(const short8*)(bptr + i * 512);

    __syncthreads();

    // ---- Phase B: 32x32x16 MFMA GEMM  out[m, n=co] = sum_k Z[m,k]W^T[n,k]
    const int arow = mt * 32 + r31;
    const char* abase = (const char*)Zl + (size_t)arow * (SROW * 2);
    const int aswz = ((arow >> 1) & 7) << 4;
    // 4 swizzled base pointers; all 36 ds_reads use immediate offsets.
    const char* pj[4];
    #pragma unroll
    for (int j = 0; j < 4; ++j)
        pj[j] = abase + (((j * 32) | (u * 16)) ^ aswz);

    bf16x8 aq[4];
    #pragma unroll
    for (int i = 0; i < 4; ++i)
        aq[i] = *(const bf16x8*)(pj[i & 3] + (i >> 2) * 128);

    f32x16 acc = {};

    #pragma unroll
    for (int ks = 0; ks < 36; ++ks) {
        bf16x8 a  = aq[ks & 3];
        short8 bb = bq[ks & 7];
        if (ks + 4 < 36)
            aq[ks & 3] = *(const bf16x8*)(pj[(ks + 4) & 3] + ((ks + 4) >> 2) * 128);
        if (ks + 8 < 36)
            bq[ks & 7] = *(const short8*)(bptr + (ks + 8) * 512);
        acc = __builtin_amdgcn_mfma_f32_32x32x16_bf16(a, __builtin_bit_cast(bf16x8, bb), acc, 0, 0, 0);
    }

    // ---- Epilogue: D col=lane&31 -> co-local; row=(reg&3)+8*(reg>>2)+4*u
    const int co = nt * 32 + r31;
    const float bv = bias[co];
    float* obase = out + (((size_t)(b * CO_ + co)) * H_ + h0 + mt * 2) * W_ + w0;
    #pragma unroll
    for (int qq = 0; qq < 4; ++qq) {
        const int roff = qq * 8 + u * 4;       // m-local base, multiple of 4
        const int hl   = roff >> 4;            // 0 or 1 within this m-tile
        const int wl   = roff & 15;            // 0,4,8,12
        float4 vv = make_float4(acc[qq*4+0] + bv, acc[qq*4+1] + bv,
                                acc[qq*4+2] + bv, acc[qq*4+3] + bv);
        *(float4*)(obase + hl * W_ + wl) = vv;
    }
}

// ---- fp32 fallback (round-1 kernel, direct W layout) if ws is too small ----
#define WT 16
__device__ __forceinline__ void cswap(float &a, float &b) {
    float lo = fminf(a, b);
    float hi = fmaxf(a, b);
    a = lo; b = hi;
}
__global__ __launch_bounds__(256) void sconv_fp32(
    const float* __restrict__ x, const float* __restrict__ Coef,
    const float* __restrict__ Wg, const float* __restrict__ bias,
    float* __restrict__ out)
{
    __shared__ float Cf[81];
    __shared__ float Zl[C_ * 9 * WT];
    const int tid = threadIdx.x;
    const int bx  = blockIdx.x;
    const int wt  = bx & 7;
    const int h   = (bx >> 3) & 127;
    const int b   = bx >> 10;
    const int w0  = wt * WT;
    if (tid < 81) Cf[tid] = Coef[tid];
    __syncthreads();
    for (int task = tid; task < C_ * WT; task += 256) {
        const int c = task >> 4, wl = task & 15, w = w0 + wl;
        const float* xb = x + (b * C_ + c) * H_ * W_;
        float p[9];
        #pragma unroll
        for (int dy = 0; dy < 3; ++dy) {
            const int hy = h + dy - 1; const bool hin = (unsigned)hy < (unsigned)H_;
            #pragma unroll
            for (int dx = 0; dx < 3; ++dx) {
                const int wx = w + dx - 1; const bool win = (unsigned)wx < (unsigned)W_;
                p[dy * 3 + dx] = (hin && win) ? xb[hy * W_ + wx] : 0.0f;
            }
        }
        float v[8];
        #pragma unroll
        for (int ii = 0; ii < 8; ++ii) {
            const int i = ii + (ii >> 2);
            float acc = 0.0f;
            #pragma unroll
            for (int jj = 0; jj < 9; ++jj) acc = fmaf(Cf[i * 9 + jj], p[jj], acc);
            v[ii] = acc;
        }
        cswap(v[0], v[1]); cswap(v[2], v[3]); cswap(v[4], v[5]); cswap(v[6], v[7]);
        cswap(v[0], v[2]); cswap(v[1], v[3]); cswap(v[4], v[6]); cswap(v[5], v[7]);
        cswap(v[1], v[2]); cswap(v[5], v[6]);
        cswap(v[0], v[4]); cswap(v[1], v[5]); cswap(v[2], v[6]); cswap(v[3], v[7]);
        cswap(v[2], v[4]); cswap(v[3], v[5]);
        cswap(v[1], v[2]); cswap(v[3], v[4]); cswap(v[5], v[6]);
        const int base = c * 9 * WT + wl;
        Zl[base + 0*WT]=v[0]; Zl[base + 1*WT]=v[1]; Zl[base + 2*WT]=v[2]; Zl[base + 3*WT]=v[3];
        Zl[base + 4*WT]=p[4];
        Zl[base + 5*WT]=v[4]; Zl[base + 6*WT]=v[5]; Zl[base + 7*WT]=v[6]; Zl[base + 8*WT]=v[7];
    }
    __syncthreads();
    const int co = tid >> 1, w0l = (tid & 1) * 8;
    float acc[8];
    #pragma unroll
    for (int i = 0; i < 8; ++i) acc[i] = 0.0f;
    for (int c = 0; c < C_; ++c) {
        #pragma unroll
        for (int t = 0; t < 9; ++t) {
            const float wv = Wg[(co * C_ + c) * 9 + t];
            const float* zp = &Zl[(c * 9 + t) * WT + w0l];
            const float4 za = *(const float4*)zp;
            const float4 zb = *(const float4*)(zp + 4);
            acc[0]=fmaf(za.x,wv,acc[0]); acc[1]=fmaf(za.y,wv,acc[1]);
            acc[2]=fmaf(za.z,wv,acc[2]); acc[3]=fmaf(za.w,wv,acc[3]);
            acc[4]=fmaf(zb.x,wv,acc[4]); acc[5]=fmaf(zb.y,wv,acc[5]);
            acc[6]=fmaf(zb.z,wv,acc[6]); acc[7]=fmaf(zb.w,wv,acc[7]);
        }
    }
    const float bv = bias[co];
    float* op = out + ((b * CO_ + co) * H_ + h) * W_ + w0 + w0l;
    *(float4*)(op)     = make_float4(acc[0]+bv, acc[1]+bv, acc[2]+bv, acc[3]+bv);
    *(float4*)(op + 4) = make_float4(acc[4]+bv, acc[5]+bv, acc[6]+bv, acc[7]+bv);
}

extern "C" void kernel_launch(void* const* d_in, const int* in_sizes, int n_in,
                              void* d_out, int out_size, void* d_ws, size_t ws_size,
                              hipStream_t stream) {
    const float* x    = (const float*)d_in[0];
    const float* Coef = (const float*)d_in[1];
    const float* Wg   = (const float*)d_in[2];
    const float* bias = (const float*)d_in[3];
    float* out = (float*)d_out;

    const size_t need = (size_t)CO_ * K_ * sizeof(ushort);   // 147456 B
    if (ws_size >= need) {
        ushort* Wb = (ushort*)d_ws;
        conv_W_bf16<<<(CO_ * K_ + 255) / 256, 256, 0, stream>>>(Wg, Wb);
        sconv_mfma<<<B_ * (H_ / 4) * (W_ / 16), 512, 0, stream>>>(x, Coef, Wb, bias, out);
    } else {
        sconv_fp32<<<B_ * H_ * 8, 256, 0, stream>>>(x, Coef, Wg, bias, out);
    }
}